// Round 2
// baseline (222.405 us; speedup 1.0000x reference)
//
#include <hip/hip_runtime.h>

// out[r, 0:S]  = p = x[r, 0:S]
// out[r, S:2S] = w[r] * selu(p) + x[r, S:2S]
// S = 4096, x is (S, 2S) fp32 row-major. Pure elementwise, memory-bound.
//
// R7-retry: identical to R7 (previous bench died on container infra, not
// on the kernel — no compile/verify/counter evidence against it).
//
// R7: MLP + STREAM DECOUPLING on top of R6's NT-loads/plain-stores winner.
//  - 2 rows per block: 16 float4 loads in flight per thread (16 KiB/wave)
//    vs 8 before. Streaming BW at the last ~20% is bytes-in-flight-limited;
//    occupancy drops ~8->6 waves/SIMD but in-flight bytes/CU rises
//    256 KiB -> ~384 KiB.
//  - Phase order: all p-loads -> all q-loads -> p-copy stores -> compute +
//    q-stores. Each p-store waits only on its own load (vmcnt staging), so
//    the pure-copy writeback stream overlaps the q-load arrivals instead of
//    serializing behind the full 16-load burst.
//  - Keep: NT loads (read-once, don't allocate in L2 -> L2 stays free for
//    the write stream), plain cached stores (deferred writeback past
//    kernel-end; R4 showed NT stores charge all 131 MB in-kernel at ~30%
//    peak BW).

#define SIZE  4096
#define HALF4 (SIZE / 4)          // 1024 float4 per half-row
#define ROW4  (2 * HALF4)         // 2048 float4 per full row
#define RPB   2                   // rows per block

typedef float f32x4 __attribute__((ext_vector_type(4)));

__device__ __forceinline__ f32x4 selu_fma(f32x4 p, f32x4 q, float w) {
    const float scale = 1.0507009873554804934f;
    const float alpha = 1.6732632423543772848f;
    f32x4 r;
#pragma unroll
    for (int i = 0; i < 4; ++i) {
        float sp = p[i] > 0.0f ? scale * p[i]
                               : scale * alpha * (__expf(p[i]) - 1.0f);
        r[i] = w * sp + q[i];
    }
    return r;
}

__global__ __launch_bounds__(256) void selu_residual_kernel(
    const f32x4* __restrict__ x4,
    const float* __restrict__ weight,
    f32x4* __restrict__ out4)
{
    const unsigned row0 = blockIdx.x * RPB;      // 2 consecutive rows/block
    const unsigned t    = threadIdx.x;

    float w[RPB];
#pragma unroll
    for (int r = 0; r < RPB; ++r) w[r] = weight[row0 + r];  // block-uniform

    f32x4 p[RPB][4], q[RPB][4];

    // Phase 1a: issue ALL p loads first (copy stream).
#pragma unroll
    for (int r = 0; r < RPB; ++r) {
        const unsigned base = (row0 + r) * ROW4;
#pragma unroll
        for (int k = 0; k < 4; ++k)
            p[r][k] = __builtin_nontemporal_load(&x4[base + t + k * 256]);
    }
    // Phase 1b: then ALL q loads (compute stream). 16 loads outstanding.
#pragma unroll
    for (int r = 0; r < RPB; ++r) {
        const unsigned base = (row0 + r) * ROW4;
#pragma unroll
        for (int k = 0; k < 4; ++k)
            q[r][k] = __builtin_nontemporal_load(&x4[base + HALF4 + t + k * 256]);
    }

    // Phase 2: p copy-out. Store p[r][k] waits only on its own load
    // (vmcnt staging), so this write stream drains while q loads are
    // still in flight.
#pragma unroll
    for (int r = 0; r < RPB; ++r) {
        const unsigned base = (row0 + r) * ROW4;
#pragma unroll
        for (int k = 0; k < 4; ++k)
            out4[base + t + k * 256] = p[r][k];
    }

    // Phase 3: selu + residual, q-half stores.
#pragma unroll
    for (int r = 0; r < RPB; ++r) {
        const unsigned base = (row0 + r) * ROW4;
#pragma unroll
        for (int k = 0; k < 4; ++k)
            out4[base + HALF4 + t + k * 256] = selu_fma(p[r][k], q[r][k], w[r]);
    }
}

extern "C" void kernel_launch(void* const* d_in, const int* in_sizes, int n_in,
                              void* d_out, int out_size, void* d_ws, size_t ws_size,
                              hipStream_t stream) {
    const f32x4* x4     = (const f32x4*)d_in[0];
    const float* weight = (const float*)d_in[1];
    f32x4*       out4   = (f32x4*)d_out;

    // 2 rows per block: 2048 blocks x 256 threads; each thread does
    // 8 float4-pairs (2 rows x 1024 float4 per half-row / 256 threads).
    selu_residual_kernel<<<SIZE / RPB, 256, 0, stream>>>(x4, weight, out4);
}

// Round 5
// 220.601 us; speedup vs baseline: 1.0082x; 1.0082x over previous
//
#include <hip/hip_runtime.h>

// out[r, 0:S]  = p = x[r, 0:S]
// out[r, S:2S] = w[r] * selu(p) + x[r, S:2S]
// S = 4096, x is (S, 2S) fp32 row-major. Pure elementwise, memory-bound.
//
// R8-retry2: identical to R8 (two infra failures in a row — container
// death, then GPU acquisition timeout; the R8 experiment has not yet
// actually run, and there is no evidence against it).
//
// R8: R6 (1 row/block, best measured 218.8) + phase-decoupled ordering,
// WITHOUT R7's rows-per-block occupancy cost (R7: 16 loads/thread, 6
// waves/SIMD -> 222.4, refuted the bytes-in-flight theory; TLP wins).
//  - Load order: p[0..3] first, then q[0..3]. Store order: all p-copy
//    stores first, then compute + q-stores. Store p[k] waits only
//    vmcnt(7-k): the copy writeback stream starts draining after the
//    FIRST load returns, overlapping the q-load arrivals, instead of
//    interleaving p/q loads and pairing stores per-k.
//  - Keep: NT loads (read-once, keep L2 for the write stream; R3 219 vs
//    R4/R5 231 with plain loads), plain cached stores (deferred
//    writeback; R4 showed NT stores charge all 131 MB in-kernel at ~30%
//    peak BW), 256 threads, 4096 blocks, 8 float4 loads/thread.

#define SIZE  4096
#define HALF4 (SIZE / 4)          // 1024 float4 per half-row
#define ROW4  (2 * HALF4)         // 2048 float4 per full row

typedef float f32x4 __attribute__((ext_vector_type(4)));

__device__ __forceinline__ f32x4 selu_fma(f32x4 p, f32x4 q, float w) {
    const float scale = 1.0507009873554804934f;
    const float alpha = 1.6732632423543772848f;
    f32x4 r;
#pragma unroll
    for (int i = 0; i < 4; ++i) {
        float sp = p[i] > 0.0f ? scale * p[i]
                               : scale * alpha * (__expf(p[i]) - 1.0f);
        r[i] = w * sp + q[i];
    }
    return r;
}

__global__ __launch_bounds__(256) void selu_residual_kernel(
    const f32x4* __restrict__ x4,
    const float* __restrict__ weight,
    f32x4* __restrict__ out4)
{
    const unsigned row  = blockIdx.x;            // 0..4095
    const float    w    = weight[row];           // block-uniform scalar load
    const unsigned base = row * ROW4;
    const unsigned t    = threadIdx.x;

    f32x4 p[4], q[4];

    // Phase 1a: p loads first (copy stream).
#pragma unroll
    for (int k = 0; k < 4; ++k)
        p[k] = __builtin_nontemporal_load(&x4[base + t + k * 256]);
    // Phase 1b: q loads (compute stream). 8 loads outstanding.
#pragma unroll
    for (int k = 0; k < 4; ++k)
        q[k] = __builtin_nontemporal_load(&x4[base + HALF4 + t + k * 256]);

    // Phase 2: p copy-out. Store p[k] waits only vmcnt(7-k) -> writeback
    // begins after the first load returns, overlapping q-load arrivals.
#pragma unroll
    for (int k = 0; k < 4; ++k)
        out4[base + t + k * 256] = p[k];

    // Phase 3: selu + residual, q-half stores.
#pragma unroll
    for (int k = 0; k < 4; ++k)
        out4[base + HALF4 + t + k * 256] = selu_fma(p[k], q[k], w);
}

extern "C" void kernel_launch(void* const* d_in, const int* in_sizes, int n_in,
                              void* d_out, int out_size, void* d_ws, size_t ws_size,
                              hipStream_t stream) {
    const f32x4* x4     = (const f32x4*)d_in[0];
    const float* weight = (const float*)d_in[1];
    f32x4*       out4   = (f32x4*)d_out;

    // One block per row: 4096 blocks x 256 threads; each thread does
    // 4 float4-pairs (1024 float4 per half-row / 256 threads).
    selu_residual_kernel<<<SIZE, 256, 0, stream>>>(x4, weight, out4);
}